// Round 1
// baseline (2093.383 us; speedup 1.0000x reference)
//
#include <hip/hip_runtime.h>
#include <hip/hip_bf16.h>

#define NN 10000
#define NE 320000
#define HD 128
#define TILE 128
#define NTILES (NE / TILE)   // 2500 exactly
#define HSTR 132             // padded LDS row stride (words), keeps float4 alignment

// ---------------- CSR build (edges sorted by dst) ----------------
__global__ void hist_kernel(const int* __restrict__ dst, int* __restrict__ cnt) {
    int e = blockIdx.x * blockDim.x + threadIdx.x;
    if (e < NE) atomicAdd(&cnt[dst[e]], 1);
}

__global__ void scan_kernel(const int* __restrict__ cnt, int* __restrict__ rs, int* __restrict__ cur) {
    __shared__ int part[256];
    int t = threadIdx.x;
    const int CH = (NN + 255) / 256;  // 40
    int base = t * CH;
    int s = 0;
    for (int i = 0; i < CH; i++) {
        int idx = base + i;
        if (idx < NN) s += cnt[idx];
    }
    part[t] = s;
    __syncthreads();
    for (int off = 1; off < 256; off <<= 1) {
        int v = (t >= off) ? part[t - off] : 0;
        __syncthreads();
        part[t] += v;
        __syncthreads();
    }
    int run = part[t] - s;  // exclusive prefix of this thread's chunk
    for (int i = 0; i < CH; i++) {
        int idx = base + i;
        if (idx < NN) {
            rs[idx] = run;
            cur[idx] = run;
            run += cnt[idx];
        }
    }
    if (t == 255) rs[NN] = run;   // == NE
}

__global__ void scatter_kernel(const int* __restrict__ src, const int* __restrict__ dst,
                               int* __restrict__ cur, int* __restrict__ ssrc) {
    int e = blockIdx.x * blockDim.x + threadIdx.x;
    if (e < NE) {
        int p = atomicAdd(&cur[dst[e]], 1);
        ssrc[p] = src[e];
    }
}

__global__ void nodeof_kernel(const int* __restrict__ rs, int* __restrict__ nof) {
    int n = blockIdx.x * blockDim.x + threadIdx.x;
    if (n < NN) {
        int b = rs[n], e = rs[n + 1];
        for (int s = b; s < e; s++) nof[s] = n;
    }
}

// ---------------- per-node layer-1 factorization ----------------
// A[i] = x_i @ (W0_top - W0_bot) + b0   (dst side)
// B[j] = x_j @ W0_bot                   (src side)
template<int D>
__global__ __launch_bounds__(256)
void nodeAB_kernel(const float* __restrict__ x, const float* __restrict__ W0,
                   const float* __restrict__ b0, float* __restrict__ A, float* __restrict__ Bm) {
    __shared__ float xs[8 * 128];
    int t = threadIdx.x;
    int n0 = blockIdx.x * 8;
    for (int i = t; i < 8 * D; i += 256) {
        int n = i / D, d = i % D;
        xs[n * 128 + d] = x[(size_t)(n0 + n) * D + d];
    }
    __syncthreads();
    int c = t & 127;
    int h = t >> 7;   // 0/1 -> nodes h*4 .. h*4+3
    float a[4], b[4];
    float bias = b0[c];
#pragma unroll
    for (int n = 0; n < 4; n++) { a[n] = bias; b[n] = 0.f; }
    for (int d = 0; d < D; d++) {
        float wt = W0[d * HD + c];
        float wb = W0[(D + d) * HD + c];
        float wd = wt - wb;
#pragma unroll
        for (int n = 0; n < 4; n++) {
            float xv = xs[(h * 4 + n) * 128 + d];
            a[n] += xv * wd;
            b[n] += xv * wb;
        }
    }
#pragma unroll
    for (int n = 0; n < 4; n++) {
        int gn = n0 + h * 4 + n;
        A[(size_t)gn * HD + c] = a[n];
        Bm[(size_t)gn * HD + c] = b[n];
    }
}

// ---------------- fused per-edge layers 2+3 + segmented aggregation ----------------
template<int DOUTB>
__global__ __launch_bounds__(256)
void edge_kernel(const float* __restrict__ A, const float* __restrict__ Bm,
                 const float* __restrict__ W1, const float* __restrict__ b1,
                 const float* __restrict__ W2g, const float* __restrict__ b2,
                 const int* __restrict__ ssrc, const int* __restrict__ nof,
                 float* __restrict__ out) {
    __shared__ __align__(16) float W1s[HD * HD];      // 64 KB, [k][c]
    __shared__ __align__(16) float Hs[HD * HSTR];     // 66 KB: h1T [k][e] -> h2T [k][e] -> m [e][c]
    __shared__ float b1s[HD];
    __shared__ float b2s[DOUTB];
    __shared__ int s_node[TILE];
    __shared__ int s_src[TILE];

    int t = threadIdx.x;
    {
        const float4* W1v = (const float4*)W1;
        float4* W1sv = (float4*)W1s;
        for (int i = t; i < HD * HD / 4; i += 256) W1sv[i] = W1v[i];
    }
    if (t < HD) b1s[t] = b1[t];
    if (t < DOUTB) b2s[t] = b2[t];

    int cg = t & 15;
    int eg = t >> 4;
    int cb = cg * 8;
    int eb = eg * 8;

    for (int tile = blockIdx.x; tile < NTILES; tile += gridDim.x) {
        int ts = tile * TILE;
        __syncthreads();   // staging done (iter 0) / prev tile fully consumed
        if (t < TILE) {
            int s = ts + t;
            s_node[t] = nof[s];
            s_src[t] = ssrc[s];
        }
        __syncthreads();
        // h1 fill, transposed: Hs[c*HSTR + e] = relu(A[dst][c] + B[src][c])
        for (int i = t; i < TILE * HD; i += 256) {
            int e = i >> 7, c = i & 127;
            float v = A[(size_t)s_node[e] * HD + c] + Bm[(size_t)s_src[e] * HD + c];
            Hs[c * HSTR + e] = fmaxf(v, 0.f);
        }
        __syncthreads();
        // ---- layer 2: h2 = relu(h1 @ W1 + b1), 8 edges x 8 channels per thread ----
        float acc[8][8];
#pragma unroll
        for (int i = 0; i < 8; i++)
#pragma unroll
            for (int j = 0; j < 8; j++) acc[i][j] = b1s[cb + j];
        for (int k = 0; k < HD; k++) {
            float4 h0 = *(const float4*)&Hs[k * HSTR + eb];
            float4 h1v = *(const float4*)&Hs[k * HSTR + eb + 4];
            float4 w0 = *(const float4*)&W1s[k * HD + cb];
            float4 w1 = *(const float4*)&W1s[k * HD + cb + 4];
            float hh[8] = {h0.x, h0.y, h0.z, h0.w, h1v.x, h1v.y, h1v.z, h1v.w};
            float ww[8] = {w0.x, w0.y, w0.z, w0.w, w1.x, w1.y, w1.z, w1.w};
#pragma unroll
            for (int i = 0; i < 8; i++)
#pragma unroll
                for (int j = 0; j < 8; j++) acc[i][j] += hh[i] * ww[j];
        }
        __syncthreads();   // everyone done reading h1T
        // write h2 transposed [c][e] (with relu) back into Hs
#pragma unroll
        for (int j = 0; j < 8; j++) {
            float4 v0 = make_float4(fmaxf(acc[0][j], 0.f), fmaxf(acc[1][j], 0.f),
                                    fmaxf(acc[2][j], 0.f), fmaxf(acc[3][j], 0.f));
            float4 v1 = make_float4(fmaxf(acc[4][j], 0.f), fmaxf(acc[5][j], 0.f),
                                    fmaxf(acc[6][j], 0.f), fmaxf(acc[7][j], 0.f));
            *(float4*)&Hs[(cb + j) * HSTR + eb] = v0;
            *(float4*)&Hs[(cb + j) * HSTR + eb + 4] = v1;
        }
        __syncthreads();
        // ---- layer 3: m = h2 @ W2 + b2 (no relu), W2 from global (L1/L2 resident) ----
        float acc2[8][8];
        if (cb < DOUTB) {
#pragma unroll
            for (int i = 0; i < 8; i++)
#pragma unroll
                for (int j = 0; j < 8; j++) acc2[i][j] = b2s[cb + j];
            for (int k = 0; k < HD; k++) {
                float4 h0 = *(const float4*)&Hs[k * HSTR + eb];
                float4 h1v = *(const float4*)&Hs[k * HSTR + eb + 4];
                float4 w0 = *(const float4*)&W2g[k * DOUTB + cb];
                float4 w1 = *(const float4*)&W2g[k * DOUTB + cb + 4];
                float hh[8] = {h0.x, h0.y, h0.z, h0.w, h1v.x, h1v.y, h1v.z, h1v.w};
                float ww[8] = {w0.x, w0.y, w0.z, w0.w, w1.x, w1.y, w1.z, w1.w};
#pragma unroll
                for (int i = 0; i < 8; i++)
#pragma unroll
                    for (int j = 0; j < 8; j++) acc2[i][j] += hh[i] * ww[j];
            }
        }
        __syncthreads();   // everyone done reading h2T
        // write m in [e][c] layout for aggregation
        if (cb < DOUTB) {
#pragma unroll
            for (int i = 0; i < 8; i++) {
                *(float4*)&Hs[(eb + i) * HSTR + cb] =
                    make_float4(acc2[i][0], acc2[i][1], acc2[i][2], acc2[i][3]);
                *(float4*)&Hs[(eb + i) * HSTR + cb + 4] =
                    make_float4(acc2[i][4], acc2[i][5], acc2[i][6], acc2[i][7]);
            }
        }
        __syncthreads();
        // ---- segmented sum over sorted dst (few atomics: ~#distinct nodes per tile) ----
        if (t < DOUTB) {
            int c = t;
            float run = 0.f;
            int prev = s_node[0];
            for (int s = 0; s < TILE; s++) {
                int nd = s_node[s];
                if (nd != prev) {
                    atomicAdd(&out[(size_t)prev * DOUTB + c], run);
                    run = 0.f;
                    prev = nd;
                }
                run += Hs[s * HSTR + c];
            }
            atomicAdd(&out[(size_t)prev * DOUTB + c], run);
        }
        // loop-top barrier protects Hs/s_node reuse
    }
}

extern "C" void kernel_launch(void* const* d_in, const int* in_sizes, int n_in,
                              void* d_out, int out_size, void* d_ws, size_t ws_size,
                              hipStream_t stream) {
    const float* x = (const float*)d_in[0];
    const int* ei = (const int*)d_in[2];
    const int* src = ei;        // edge_index[0]
    const int* dst = ei + NE;   // edge_index[1]
    const float* W[4][3];
    const float* bs[4][3];
    for (int b = 0; b < 4; b++)
        for (int l = 0; l < 3; l++) {
            W[b][l]  = (const float*)d_in[4 + b * 6 + l * 2];
            bs[b][l] = (const float*)d_in[4 + b * 6 + l * 2 + 1];
        }

    float* A   = (float*)d_ws;
    float* Bm  = A + (size_t)NN * HD;
    float* x0  = Bm + (size_t)NN * HD;
    float* x1  = x0 + (size_t)NN * HD;
    int* cnt   = (int*)(x1 + (size_t)NN * HD);
    int* rs    = cnt + NN;
    int* cur   = rs + NN + 1;
    int* ssrc  = cur + NN;
    int* nof   = ssrc + NE;
    float* out = (float*)d_out;

    // CSR build (deterministic per call)
    hipMemsetAsync(cnt, 0, NN * sizeof(int), stream);
    hist_kernel<<<(NE + 255) / 256, 256, 0, stream>>>(dst, cnt);
    scan_kernel<<<1, 256, 0, stream>>>(cnt, rs, cur);
    scatter_kernel<<<(NE + 255) / 256, 256, 0, stream>>>(src, dst, cur, ssrc);
    nodeof_kernel<<<(NN + 255) / 256, 256, 0, stream>>>(rs, nof);

    // block 0 (input dim 4)
    nodeAB_kernel<4><<<NN / 8, 256, 0, stream>>>(x, W[0][0], bs[0][0], A, Bm);
    hipMemsetAsync(x0, 0, (size_t)NN * HD * sizeof(float), stream);
    edge_kernel<128><<<1250, 256, 0, stream>>>(A, Bm, W[0][1], bs[0][1], W[0][2], bs[0][2], ssrc, nof, x0);
    // block 1
    nodeAB_kernel<128><<<NN / 8, 256, 0, stream>>>(x0, W[1][0], bs[1][0], A, Bm);
    hipMemsetAsync(x1, 0, (size_t)NN * HD * sizeof(float), stream);
    edge_kernel<128><<<1250, 256, 0, stream>>>(A, Bm, W[1][1], bs[1][1], W[1][2], bs[1][2], ssrc, nof, x1);
    // block 2
    nodeAB_kernel<128><<<NN / 8, 256, 0, stream>>>(x1, W[2][0], bs[2][0], A, Bm);
    hipMemsetAsync(x0, 0, (size_t)NN * HD * sizeof(float), stream);
    edge_kernel<128><<<1250, 256, 0, stream>>>(A, Bm, W[2][1], bs[2][1], W[2][2], bs[2][2], ssrc, nof, x0);
    // block 3 (out dim 16) -> d_out directly
    nodeAB_kernel<128><<<NN / 8, 256, 0, stream>>>(x0, W[3][0], bs[3][0], A, Bm);
    hipMemsetAsync(out, 0, (size_t)NN * 16 * sizeof(float), stream);
    edge_kernel<16><<<1250, 256, 0, stream>>>(A, Bm, W[3][1], bs[3][1], W[3][2], bs[3][2], ssrc, nof, out);
}

// Round 2
// 450.638 us; speedup vs baseline: 4.6454x; 4.6454x over previous
//
#include <hip/hip_runtime.h>
#include <hip/hip_bf16.h>

#define NN 10000
#define NE 320000
#define HD 128
#define TILE 128
#define NTILES (NE / TILE)   // 2500 exactly

typedef __attribute__((ext_vector_type(8))) short s16x8;
typedef __attribute__((ext_vector_type(4))) short s16x4;
typedef __attribute__((ext_vector_type(4))) float f32x4;

__device__ __forceinline__ short f2bf(float f) {
    union { float f; unsigned u; } v; v.f = f;
    unsigned r = v.u + 0x7FFFu + ((v.u >> 16) & 1u);   // RNE
    return (short)(r >> 16);
}

// ---------------- CSR build (edges sorted by dst) ----------------
__global__ void hist_kernel(const int* __restrict__ dst, int* __restrict__ cnt) {
    int e = blockIdx.x * blockDim.x + threadIdx.x;
    if (e < NE) atomicAdd(&cnt[dst[e]], 1);
}

__global__ void scan_kernel(const int* __restrict__ cnt, int* __restrict__ rs, int* __restrict__ cur) {
    __shared__ int part[256];
    int t = threadIdx.x;
    const int CH = (NN + 255) / 256;  // 40
    int base = t * CH;
    int s = 0;
    for (int i = 0; i < CH; i++) {
        int idx = base + i;
        if (idx < NN) s += cnt[idx];
    }
    part[t] = s;
    __syncthreads();
    for (int off = 1; off < 256; off <<= 1) {
        int v = (t >= off) ? part[t - off] : 0;
        __syncthreads();
        part[t] += v;
        __syncthreads();
    }
    int run = part[t] - s;
    for (int i = 0; i < CH; i++) {
        int idx = base + i;
        if (idx < NN) {
            rs[idx] = run;
            cur[idx] = run;
            run += cnt[idx];
        }
    }
    if (t == 255) rs[NN] = run;
}

__global__ void scatter_kernel(const int* __restrict__ src, const int* __restrict__ dst,
                               int* __restrict__ cur, int* __restrict__ ssrc) {
    int e = blockIdx.x * blockDim.x + threadIdx.x;
    if (e < NE) {
        int p = atomicAdd(&cur[dst[e]], 1);
        ssrc[p] = src[e];
    }
}

__global__ void nodeof_kernel(const int* __restrict__ rs, int* __restrict__ nof) {
    int n = blockIdx.x * blockDim.x + threadIdx.x;
    if (n < NN) {
        int b = rs[n], e = rs[n + 1];
        for (int s = b; s < e; s++) nof[s] = n;
    }
}

// ---------------- weight prep: transpose + bf16 ----------------
// m = 2b+l: l=0 -> W[b][1] (128x128), l=1 -> W[b][2] (128xDOUT)
// dst: W1T[b] at l*65536.. : [c][k] bf16
struct WPtrs { const float* w[8]; };

__global__ void prep_weights(WPtrs p, ushort* __restrict__ dst) {
    int tid = blockIdx.x * 256 + threadIdx.x;
    int m, idx;
    if (tid < 7 * 16384) { m = tid >> 14; idx = tid & 16383; }
    else if (tid < 7 * 16384 + 2048) { m = 7; idx = tid - 7 * 16384; }
    else return;
    int b = m >> 1, l = m & 1;
    int C = (m == 7) ? 16 : 128;
    int k = idx / C, c = idx % C;
    float v = p.w[m][k * C + c];
    dst[l * 65536 + b * 16384 + c * 128 + k] = (ushort)f2bf(v);
}

// ---------------- per-node layer-1 factorization (f32, unchanged) ----------------
template<int D>
__global__ __launch_bounds__(256)
void nodeAB_kernel(const float* __restrict__ x, const float* __restrict__ W0,
                   const float* __restrict__ b0, float* __restrict__ A, float* __restrict__ Bm) {
    __shared__ float xs[8 * 128];
    int t = threadIdx.x;
    int n0 = blockIdx.x * 8;
    for (int i = t; i < 8 * D; i += 256) {
        int n = i / D, d = i % D;
        xs[n * 128 + d] = x[(size_t)(n0 + n) * D + d];
    }
    __syncthreads();
    int c = t & 127;
    int h = t >> 7;
    float a[4], b[4];
    float bias = b0[c];
#pragma unroll
    for (int n = 0; n < 4; n++) { a[n] = bias; b[n] = 0.f; }
    for (int d = 0; d < D; d++) {
        float wt = W0[d * HD + c];
        float wb = W0[(D + d) * HD + c];
        float wd = wt - wb;
#pragma unroll
        for (int n = 0; n < 4; n++) {
            float xv = xs[(h * 4 + n) * 128 + d];
            a[n] += xv * wd;
            b[n] += xv * wb;
        }
    }
#pragma unroll
    for (int n = 0; n < 4; n++) {
        int gn = n0 + h * 4 + n;
        A[(size_t)gn * HD + c] = a[n];
        Bm[(size_t)gn * HD + c] = b[n];
    }
}

// ---------------- MFMA edge kernel: layers 2+3 + segmented aggregation ----------------
// Layer 2:  D[c][e] = sum_k W1T[c][k] * h1T[k][e]   (A = W1T global, B^T = HA LDS)
// Layer 3:  D[c][e] = sum_k W2T[c][k] * h2T[k][e]   (A = W2T global, B^T = HB LDS)
// C/D frag: col(e) = lane&15, row(c) = (lane>>4)*4 + reg   [m89/m91 verified]
template<int DOUTB>
__global__ __launch_bounds__(256, 2)
void edge_mfma_kernel(const float* __restrict__ Af, const float* __restrict__ Bf,
                      const ushort* __restrict__ W1T, const float* __restrict__ b1,
                      const ushort* __restrict__ W2T, const float* __restrict__ b2,
                      const int* __restrict__ ssrc, const int* __restrict__ nof,
                      float* __restrict__ out) {
    __shared__ __align__(16) ushort HA[128 * 136];   // h1 [e][k] bf16; later MS f32[64][132]
    __shared__ __align__(16) ushort HB[128 * 136];   // h2 [e][k] bf16
    __shared__ int s_node[TILE];
    __shared__ int s_src[TILE];

    const int t = threadIdx.x;
    const int lane = t & 63;
    const int w = t >> 6;
    const int lr = lane & 15;   // row/col within 16x16 tile
    const int lg = lane >> 4;   // k-subgroup / reg-row group
    const int wr = w >> 1;      // layer-2 c-block (64)
    const int wc = w & 1;       // layer-2 e-block (64)

    const int ts = blockIdx.x * TILE;
    if (t < TILE) { s_node[t] = nof[ts + t]; s_src[t] = ssrc[ts + t]; }

    // hoisted per-lane biases (L2-resident scalar loads, once per wg)
    float bias2[4][4];
#pragma unroll
    for (int m = 0; m < 4; m++)
#pragma unroll
        for (int r = 0; r < 4; r++)
            bias2[m][r] = b1[wr * 64 + m * 16 + lg * 4 + r];

    constexpr int MT3 = (DOUTB == 128) ? 4 : 1;
    constexpr int NT3 = (DOUTB == 128) ? 4 : 2;
    const int cBase3 = (DOUTB == 128) ? wr * 64 : 0;
    const int eBase3 = (DOUTB == 128) ? wc * 64 : w * 32;
    float bias3[MT3][4];
#pragma unroll
    for (int m = 0; m < MT3; m++)
#pragma unroll
        for (int r = 0; r < 4; r++)
            bias3[m][r] = b2[cBase3 + m * 16 + lg * 4 + r];

    __syncthreads();

    // ---- h1 fill: HA[e][k] = bf16(relu(A[dst][k] + B[src][k])), f32 gather ----
    for (int i = t; i < TILE * 16; i += 256) {
        const int e = i >> 4, cg = i & 15;
        const size_t an = (size_t)s_node[e] * HD + cg * 8;
        const size_t bn = (size_t)s_src[e] * HD + cg * 8;
        const float4 a0 = *(const float4*)(Af + an);
        const float4 a1 = *(const float4*)(Af + an + 4);
        const float4 b0v = *(const float4*)(Bf + bn);
        const float4 b1v = *(const float4*)(Bf + bn + 4);
        s16x8 hv;
        hv[0] = f2bf(fmaxf(a0.x + b0v.x, 0.f));
        hv[1] = f2bf(fmaxf(a0.y + b0v.y, 0.f));
        hv[2] = f2bf(fmaxf(a0.z + b0v.z, 0.f));
        hv[3] = f2bf(fmaxf(a0.w + b0v.w, 0.f));
        hv[4] = f2bf(fmaxf(a1.x + b1v.x, 0.f));
        hv[5] = f2bf(fmaxf(a1.y + b1v.y, 0.f));
        hv[6] = f2bf(fmaxf(a1.z + b1v.z, 0.f));
        hv[7] = f2bf(fmaxf(a1.w + b1v.w, 0.f));
        *(s16x8*)(HA + e * 136 + cg * 8) = hv;
    }
    __syncthreads();

    // ---- layer 2: wave computes c[wr*64,+64) x e[wc*64,+64) ----
    f32x4 acc[4][4];
#pragma unroll
    for (int m = 0; m < 4; m++)
#pragma unroll
        for (int n = 0; n < 4; n++) {
            f32x4 v; v[0] = bias2[m][0]; v[1] = bias2[m][1]; v[2] = bias2[m][2]; v[3] = bias2[m][3];
            acc[m][n] = v;
        }
#pragma unroll
    for (int ks = 0; ks < 4; ks++) {
        const int k0 = ks * 32 + lg * 8;
        s16x8 afr[4], bfr[4];
#pragma unroll
        for (int m = 0; m < 4; m++)
            afr[m] = *(const s16x8*)(W1T + (size_t)(wr * 64 + m * 16 + lr) * HD + k0);
#pragma unroll
        for (int n = 0; n < 4; n++)
            bfr[n] = *(const s16x8*)(HA + (wc * 64 + n * 16 + lr) * 136 + k0);
#pragma unroll
        for (int m = 0; m < 4; m++)
#pragma unroll
            for (int n = 0; n < 4; n++)
                acc[m][n] = __builtin_amdgcn_mfma_f32_16x16x32_bf16(afr[m], bfr[n], acc[m][n], 0, 0, 0);
    }
    // write h2 = relu(acc) to HB[e][c] — 4 consecutive c per frag -> b64
#pragma unroll
    for (int m = 0; m < 4; m++)
#pragma unroll
        for (int n = 0; n < 4; n++) {
            const int e = wc * 64 + n * 16 + lr;
            const int c0 = wr * 64 + m * 16 + lg * 4;
            s16x4 hv;
            hv[0] = f2bf(fmaxf(acc[m][n][0], 0.f));
            hv[1] = f2bf(fmaxf(acc[m][n][1], 0.f));
            hv[2] = f2bf(fmaxf(acc[m][n][2], 0.f));
            hv[3] = f2bf(fmaxf(acc[m][n][3], 0.f));
            *(s16x4*)(HB + e * 136 + c0) = hv;
        }
    __syncthreads();

    // ---- layer 3: m[c][e] (no relu) ----
    f32x4 acc2[MT3][NT3];
#pragma unroll
    for (int m = 0; m < MT3; m++)
#pragma unroll
        for (int n = 0; n < NT3; n++) {
            f32x4 v; v[0] = bias3[m][0]; v[1] = bias3[m][1]; v[2] = bias3[m][2]; v[3] = bias3[m][3];
            acc2[m][n] = v;
        }
#pragma unroll
    for (int ks = 0; ks < 4; ks++) {
        const int k0 = ks * 32 + lg * 8;
        s16x8 afr[MT3], bfr[NT3];
#pragma unroll
        for (int m = 0; m < MT3; m++)
            afr[m] = *(const s16x8*)(W2T + (size_t)(cBase3 + m * 16 + lr) * HD + k0);
#pragma unroll
        for (int n = 0; n < NT3; n++)
            bfr[n] = *(const s16x8*)(HB + (eBase3 + n * 16 + lr) * 136 + k0);
#pragma unroll
        for (int m = 0; m < MT3; m++)
#pragma unroll
            for (int n = 0; n < NT3; n++)
                acc2[m][n] = __builtin_amdgcn_mfma_f32_16x16x32_bf16(afr[m], bfr[n], acc2[m][n], 0, 0, 0);
    }

    // ---- staged aggregation in two 64-edge halves (MS overlays dead HA) ----
    float* MS = (float*)HA;   // f32 [64][132]
#pragma unroll
    for (int half = 0; half < 2; half++) {
        if ((eBase3 >> 6) == half) {
            const int eloc = eBase3 & 63;
#pragma unroll
            for (int m = 0; m < MT3; m++)
#pragma unroll
                for (int n = 0; n < NT3; n++)
                    *(f32x4*)(MS + (eloc + n * 16 + lr) * 132 + cBase3 + m * 16 + lg * 4) = acc2[m][n];
        }
        __syncthreads();
        {
            constexpr int CPT = 256 / DOUTB;   // chunks per half
            constexpr int EPC = 64 / CPT;      // edges per chunk
            const int c = t % DOUTB;
            const int ch = t / DOUTB;
            const int eb = ch * EPC;
            float run = 0.f;
            int prev = s_node[half * 64 + eb];
            for (int s = 0; s < EPC; s++) {
                const int nd = s_node[half * 64 + eb + s];
                const float v = MS[(eb + s) * 132 + c];
                if (nd != prev) { atomicAdd(out + (size_t)prev * DOUTB + c, run); run = 0.f; prev = nd; }
                run += v;
            }
            atomicAdd(out + (size_t)prev * DOUTB + c, run);
        }
        __syncthreads();
    }
}

extern "C" void kernel_launch(void* const* d_in, const int* in_sizes, int n_in,
                              void* d_out, int out_size, void* d_ws, size_t ws_size,
                              hipStream_t stream) {
    const float* x = (const float*)d_in[0];
    const int* ei = (const int*)d_in[2];
    const int* src = ei;
    const int* dst = ei + NE;
    const float* W[4][3];
    const float* bs[4][3];
    for (int b = 0; b < 4; b++)
        for (int l = 0; l < 3; l++) {
            W[b][l]  = (const float*)d_in[4 + b * 6 + l * 2];
            bs[b][l] = (const float*)d_in[4 + b * 6 + l * 2 + 1];
        }

    float* A   = (float*)d_ws;
    float* Bm  = A + (size_t)NN * HD;
    float* x0  = Bm + (size_t)NN * HD;
    float* x1  = x0 + (size_t)NN * HD;
    ushort* WT = (ushort*)(x1 + (size_t)NN * HD);   // 131072 ushort = 256 KB
    int* cnt   = (int*)(WT + 131072);
    int* rs    = cnt + NN;
    int* cur   = rs + NN + 1;
    int* ssrc  = cur + NN;
    int* nof   = ssrc + NE;
    float* out = (float*)d_out;

    // CSR build
    hipMemsetAsync(cnt, 0, NN * sizeof(int), stream);
    hist_kernel<<<(NE + 255) / 256, 256, 0, stream>>>(dst, cnt);
    scan_kernel<<<1, 256, 0, stream>>>(cnt, rs, cur);
    scatter_kernel<<<(NE + 255) / 256, 256, 0, stream>>>(src, dst, cur, ssrc);
    nodeof_kernel<<<(NN + 255) / 256, 256, 0, stream>>>(rs, nof);

    // weight prep (transpose + bf16)
    WPtrs wp;
    for (int b = 0; b < 4; b++) { wp.w[2 * b] = W[b][1]; wp.w[2 * b + 1] = W[b][2]; }
    prep_weights<<<456, 256, 0, stream>>>(wp, WT);

    const ushort* W1T[4];
    const ushort* W2T[4];
    for (int b = 0; b < 4; b++) { W1T[b] = WT + b * 16384; W2T[b] = WT + 65536 + b * 16384; }

    // block 0
    nodeAB_kernel<4><<<NN / 8, 256, 0, stream>>>(x, W[0][0], bs[0][0], A, Bm);
    hipMemsetAsync(x0, 0, (size_t)NN * HD * sizeof(float), stream);
    edge_mfma_kernel<128><<<NTILES, 256, 0, stream>>>(A, Bm, W1T[0], bs[0][1], W2T[0], bs[0][2], ssrc, nof, x0);
    // block 1
    nodeAB_kernel<128><<<NN / 8, 256, 0, stream>>>(x0, W[1][0], bs[1][0], A, Bm);
    hipMemsetAsync(x1, 0, (size_t)NN * HD * sizeof(float), stream);
    edge_mfma_kernel<128><<<NTILES, 256, 0, stream>>>(A, Bm, W1T[1], bs[1][1], W2T[1], bs[1][2], ssrc, nof, x1);
    // block 2
    nodeAB_kernel<128><<<NN / 8, 256, 0, stream>>>(x1, W[2][0], bs[2][0], A, Bm);
    hipMemsetAsync(x0, 0, (size_t)NN * HD * sizeof(float), stream);
    edge_mfma_kernel<128><<<NTILES, 256, 0, stream>>>(A, Bm, W1T[2], bs[2][1], W2T[2], bs[2][2], ssrc, nof, x0);
    // block 3 -> d_out
    nodeAB_kernel<128><<<NN / 8, 256, 0, stream>>>(x0, W[3][0], bs[3][0], A, Bm);
    hipMemsetAsync(out, 0, (size_t)NN * 16 * sizeof(float), stream);
    edge_mfma_kernel<16><<<NTILES, 256, 0, stream>>>(A, Bm, W1T[3], bs[3][1], W2T[3], bs[3][2], ssrc, nof, out);
}

// Round 3
// 416.442 us; speedup vs baseline: 5.0268x; 1.0821x over previous
//
#include <hip/hip_runtime.h>
#include <hip/hip_bf16.h>

#define NN 10000
#define NE 320000
#define HD 128
#define TILE 128
#define NTILES (NE / TILE)   // 2500 exactly

typedef __attribute__((ext_vector_type(8))) short s16x8;
typedef __attribute__((ext_vector_type(4))) short s16x4;
typedef __attribute__((ext_vector_type(4))) float f32x4;

__device__ __forceinline__ short f2bf(float f) {
    union { float f; unsigned u; } v; v.f = f;
    unsigned r = v.u + 0x7FFFu + ((v.u >> 16) & 1u);   // RNE
    return (short)(r >> 16);
}
__device__ __forceinline__ float bf2f(short s) {
    union { unsigned u; float f; } v;
    v.u = ((unsigned)(unsigned short)s) << 16;
    return v.f;
}

// ---------------- CSR build (edges sorted by dst) + fused weight prep ----------------
struct WPtrs { const float* w[8]; };

// m = 2b+l: l=0 -> W[b][1] (128x128), l=1 -> W[b][2] (128xDOUT); dst layout [c][k] bf16
__global__ void hist_kernel(const int* __restrict__ dst, int* __restrict__ cnt,
                            WPtrs p, ushort* __restrict__ wdst) {
    int e = blockIdx.x * blockDim.x + threadIdx.x;
    if (e < NE) atomicAdd(&cnt[dst[e]], 1);
    // fused weight transpose+bf16 (independent work, saves a dispatch)
    int tid = e;
    int m, idx;
    if (tid < 7 * 16384) { m = tid >> 14; idx = tid & 16383; }
    else if (tid < 7 * 16384 + 2048) { m = 7; idx = tid - 7 * 16384; }
    else return;
    int b = m >> 1, l = m & 1;
    int C = (m == 7) ? 16 : 128;
    int k = idx / C, c = idx % C;
    float v = p.w[m][k * C + c];
    wdst[l * 65536 + b * 16384 + c * 128 + k] = (ushort)f2bf(v);
}

__global__ void scan_kernel(const int* __restrict__ cnt, int* __restrict__ rs, int* __restrict__ cur) {
    __shared__ int part[256];
    int t = threadIdx.x;
    const int CH = (NN + 255) / 256;  // 40
    int base = t * CH;
    int s = 0;
    for (int i = 0; i < CH; i++) {
        int idx = base + i;
        if (idx < NN) s += cnt[idx];
    }
    part[t] = s;
    __syncthreads();
    for (int off = 1; off < 256; off <<= 1) {
        int v = (t >= off) ? part[t - off] : 0;
        __syncthreads();
        part[t] += v;
        __syncthreads();
    }
    int run = part[t] - s;
    for (int i = 0; i < CH; i++) {
        int idx = base + i;
        if (idx < NN) {
            rs[idx] = run;
            cur[idx] = run;
            run += cnt[idx];
        }
    }
    if (t == 255) rs[NN] = run;
}

__global__ void scatter_kernel(const int* __restrict__ src, const int* __restrict__ dst,
                               int* __restrict__ cur, int* __restrict__ ssrc) {
    int e = blockIdx.x * blockDim.x + threadIdx.x;
    if (e < NE) {
        int p = atomicAdd(&cur[dst[e]], 1);
        ssrc[p] = src[e];
    }
}

__global__ void nodeof_kernel(const int* __restrict__ rs, int* __restrict__ nof) {
    int n = blockIdx.x * blockDim.x + threadIdx.x;
    if (n < NN) {
        int b = rs[n], e = rs[n + 1];
        for (int s = b; s < e; s++) nof[s] = n;
    }
}

// ---------------- per-node layer-1 factorization -> bf16 A/B, fused zero-fill ----------------
// A[i] = x_i @ (W0_top - W0_bot) + b0   (dst side)
// B[j] = x_j @ W0_bot                   (src side)
// Also zeroes zbuf (next stage's atomic accumulation target) -> removes memset dispatches.
template<int D, int ZD>
__global__ __launch_bounds__(256)
void nodeAB_kernel(const float* __restrict__ x, const float* __restrict__ W0,
                   const float* __restrict__ b0, ushort* __restrict__ A,
                   ushort* __restrict__ Bm, float* __restrict__ zbuf) {
    __shared__ float xs[8 * 128];
    int t = threadIdx.x;
    int n0 = blockIdx.x * 8;
    for (int i = t; i < 8 * D; i += 256) {
        int n = i / D, d = i % D;
        xs[n * 128 + d] = x[(size_t)(n0 + n) * D + d];
    }
    // zero-fill next-stage output rows for these 8 nodes
    for (int i = t; i < 8 * ZD; i += 256) zbuf[(size_t)n0 * ZD + i] = 0.f;
    __syncthreads();
    int c = t & 127;
    int h = t >> 7;
    float a[4], b[4];
    float bias = b0[c];
#pragma unroll
    for (int n = 0; n < 4; n++) { a[n] = bias; b[n] = 0.f; }
    for (int d = 0; d < D; d++) {
        float wt = W0[d * HD + c];
        float wb = W0[(D + d) * HD + c];
        float wd = wt - wb;
#pragma unroll
        for (int n = 0; n < 4; n++) {
            float xv = xs[(h * 4 + n) * 128 + d];
            a[n] += xv * wd;
            b[n] += xv * wb;
        }
    }
#pragma unroll
    for (int n = 0; n < 4; n++) {
        int gn = n0 + h * 4 + n;
        A[(size_t)gn * HD + c] = (ushort)f2bf(a[n]);
        Bm[(size_t)gn * HD + c] = (ushort)f2bf(b[n]);
    }
}

// ---------------- MFMA edge kernel: layers 2+3 + segmented aggregation ----------------
// Single LDS buffer HH: h1 [e][k] bf16 -> h2 [e][c] bf16 (in-place after barrier)
//                       -> MS f32[64][132] per aggregation half.
// C/D frag: col(e) = lane&15, row(c) = (lane>>4)*4 + reg   [m89/m91 verified]
template<int DOUTB>
__global__ __launch_bounds__(256, 4)
void edge_mfma_kernel(const ushort* __restrict__ Af, const ushort* __restrict__ Bf,
                      const ushort* __restrict__ W1T, const float* __restrict__ b1,
                      const ushort* __restrict__ W2T, const float* __restrict__ b2,
                      const int* __restrict__ ssrc, const int* __restrict__ nof,
                      float* __restrict__ out) {
    __shared__ __align__(16) ushort HH[128 * 136];   // 34816 B
    __shared__ int s_node[TILE];
    __shared__ int s_src[TILE];

    const int t = threadIdx.x;
    const int lane = t & 63;
    const int w = t >> 6;
    const int lr = lane & 15;
    const int lg = lane >> 4;
    const int wr = w >> 1;      // layer-2 c-block (64)
    const int wc = w & 1;       // layer-2 e-block (64)

    const int ts = blockIdx.x * TILE;
    if (t < TILE) { s_node[t] = nof[ts + t]; s_src[t] = ssrc[ts + t]; }

    float bias2[4][4];
#pragma unroll
    for (int m = 0; m < 4; m++)
#pragma unroll
        for (int r = 0; r < 4; r++)
            bias2[m][r] = b1[wr * 64 + m * 16 + lg * 4 + r];

    constexpr int MT3 = (DOUTB == 128) ? 4 : 1;
    constexpr int NT3 = (DOUTB == 128) ? 4 : 2;
    const int cBase3 = (DOUTB == 128) ? wr * 64 : 0;
    const int eBase3 = (DOUTB == 128) ? wc * 64 : w * 32;
    float bias3[MT3][4];
#pragma unroll
    for (int m = 0; m < MT3; m++)
#pragma unroll
        for (int r = 0; r < 4; r++)
            bias3[m][r] = b2[cBase3 + m * 16 + lg * 4 + r];

    __syncthreads();

    // ---- h1 fill: HH[e][k] = bf16(relu(A[dst][k] + B[src][k])), bf16 gather ----
    for (int i = t; i < TILE * 16; i += 256) {
        const int e = i >> 4, cg = i & 15;
        const s16x8 av = *(const s16x8*)(Af + (size_t)s_node[e] * HD + cg * 8);
        const s16x8 bv = *(const s16x8*)(Bf + (size_t)s_src[e] * HD + cg * 8);
        s16x8 hv;
#pragma unroll
        for (int j = 0; j < 8; j++)
            hv[j] = f2bf(fmaxf(bf2f(av[j]) + bf2f(bv[j]), 0.f));
        *(s16x8*)(HH + e * 136 + cg * 8) = hv;
    }
    __syncthreads();

    // ---- layer 2: wave computes c[wr*64,+64) x e[wc*64,+64) ----
    f32x4 acc[4][4];
#pragma unroll
    for (int m = 0; m < 4; m++)
#pragma unroll
        for (int n = 0; n < 4; n++) {
            f32x4 v; v[0] = bias2[m][0]; v[1] = bias2[m][1]; v[2] = bias2[m][2]; v[3] = bias2[m][3];
            acc[m][n] = v;
        }
#pragma unroll
    for (int ks = 0; ks < 4; ks++) {
        const int k0 = ks * 32 + lg * 8;
        s16x8 afr[4], bfr[4];
#pragma unroll
        for (int m = 0; m < 4; m++)
            afr[m] = *(const s16x8*)(W1T + (size_t)(wr * 64 + m * 16 + lr) * HD + k0);
#pragma unroll
        for (int n = 0; n < 4; n++)
            bfr[n] = *(const s16x8*)(HH + (wc * 64 + n * 16 + lr) * 136 + k0);
#pragma unroll
        for (int m = 0; m < 4; m++)
#pragma unroll
            for (int n = 0; n < 4; n++)
                acc[m][n] = __builtin_amdgcn_mfma_f32_16x16x32_bf16(afr[m], bfr[n], acc[m][n], 0, 0, 0);
    }
    __syncthreads();   // all h1 reads complete -> HH reusable

    // write h2 = relu(acc) in-place: HH[e][c]
#pragma unroll
    for (int m = 0; m < 4; m++)
#pragma unroll
        for (int n = 0; n < 4; n++) {
            const int e = wc * 64 + n * 16 + lr;
            const int c0 = wr * 64 + m * 16 + lg * 4;
            s16x4 hv;
            hv[0] = f2bf(fmaxf(acc[m][n][0], 0.f));
            hv[1] = f2bf(fmaxf(acc[m][n][1], 0.f));
            hv[2] = f2bf(fmaxf(acc[m][n][2], 0.f));
            hv[3] = f2bf(fmaxf(acc[m][n][3], 0.f));
            *(s16x4*)(HH + e * 136 + c0) = hv;
        }
    __syncthreads();

    // ---- layer 3: m[c][e] (no relu) ----
    f32x4 acc2[MT3][NT3];
#pragma unroll
    for (int m = 0; m < MT3; m++)
#pragma unroll
        for (int n = 0; n < NT3; n++) {
            f32x4 v; v[0] = bias3[m][0]; v[1] = bias3[m][1]; v[2] = bias3[m][2]; v[3] = bias3[m][3];
            acc2[m][n] = v;
        }
#pragma unroll
    for (int ks = 0; ks < 4; ks++) {
        const int k0 = ks * 32 + lg * 8;
        s16x8 afr[MT3], bfr[NT3];
#pragma unroll
        for (int m = 0; m < MT3; m++)
            afr[m] = *(const s16x8*)(W2T + (size_t)(cBase3 + m * 16 + lr) * HD + k0);
#pragma unroll
        for (int n = 0; n < NT3; n++)
            bfr[n] = *(const s16x8*)(HH + (eBase3 + n * 16 + lr) * 136 + k0);
#pragma unroll
        for (int m = 0; m < MT3; m++)
#pragma unroll
            for (int n = 0; n < NT3; n++)
                acc2[m][n] = __builtin_amdgcn_mfma_f32_16x16x32_bf16(afr[m], bfr[n], acc2[m][n], 0, 0, 0);
    }
    __syncthreads();   // all h2 reads complete -> HH reusable as MS

    // ---- staged aggregation in two 64-edge halves (MS overlays HH) ----
    float* MS = (float*)HH;   // f32 [64][132] = 33792 B < 34816 B
#pragma unroll
    for (int half = 0; half < 2; half++) {
        if ((eBase3 >> 6) == half) {
            const int eloc = eBase3 & 63;
#pragma unroll
            for (int m = 0; m < MT3; m++)
#pragma unroll
                for (int n = 0; n < NT3; n++)
                    *(f32x4*)(MS + (eloc + n * 16 + lr) * 132 + cBase3 + m * 16 + lg * 4) = acc2[m][n];
        }
        __syncthreads();
        {
            constexpr int CPT = 256 / DOUTB;   // chunks per half
            constexpr int EPC = 64 / CPT;      // edges per chunk
            const int c = t % DOUTB;
            const int ch = t / DOUTB;
            const int eb = ch * EPC;
            float run = 0.f;
            int prev = s_node[half * 64 + eb];
            for (int s = 0; s < EPC; s++) {
                const int nd = s_node[half * 64 + eb + s];
                const float v = MS[(eb + s) * 132 + c];
                if (nd != prev) { atomicAdd(out + (size_t)prev * DOUTB + c, run); run = 0.f; prev = nd; }
                run += v;
            }
            atomicAdd(out + (size_t)prev * DOUTB + c, run);
        }
        __syncthreads();
    }
}

extern "C" void kernel_launch(void* const* d_in, const int* in_sizes, int n_in,
                              void* d_out, int out_size, void* d_ws, size_t ws_size,
                              hipStream_t stream) {
    const float* x = (const float*)d_in[0];
    const int* ei = (const int*)d_in[2];
    const int* src = ei;
    const int* dst = ei + NE;
    const float* W[4][3];
    const float* bs[4][3];
    for (int b = 0; b < 4; b++)
        for (int l = 0; l < 3; l++) {
            W[b][l]  = (const float*)d_in[4 + b * 6 + l * 2];
            bs[b][l] = (const float*)d_in[4 + b * 6 + l * 2 + 1];
        }

    float* x0   = (float*)d_ws;
    float* x1   = x0 + (size_t)NN * HD;
    ushort* A   = (ushort*)(x1 + (size_t)NN * HD);
    ushort* Bm  = A + (size_t)NN * HD;
    ushort* WT  = Bm + (size_t)NN * HD;       // 131072 ushort = 256 KB
    int* cnt    = (int*)(WT + 131072);
    int* rs     = cnt + NN;
    int* cur    = rs + NN + 1;
    int* ssrc   = cur + NN;
    int* nof    = ssrc + NE;
    float* out  = (float*)d_out;

    // CSR build (+ fused weight prep in hist)
    WPtrs wp;
    for (int b = 0; b < 4; b++) { wp.w[2 * b] = W[b][1]; wp.w[2 * b + 1] = W[b][2]; }
    hipMemsetAsync(cnt, 0, NN * sizeof(int), stream);
    hist_kernel<<<(NE + 255) / 256, 256, 0, stream>>>(dst, cnt, wp, WT);
    scan_kernel<<<1, 256, 0, stream>>>(cnt, rs, cur);
    scatter_kernel<<<(NE + 255) / 256, 256, 0, stream>>>(src, dst, cur, ssrc);
    nodeof_kernel<<<(NN + 255) / 256, 256, 0, stream>>>(rs, nof);

    const ushort* W1T[4];
    const ushort* W2T[4];
    for (int b = 0; b < 4; b++) { W1T[b] = WT + b * 16384; W2T[b] = WT + 65536 + b * 16384; }

    // block 0 (nodeAB zeroes x0)
    nodeAB_kernel<4, 128><<<NN / 8, 256, 0, stream>>>(x, W[0][0], bs[0][0], A, Bm, x0);
    edge_mfma_kernel<128><<<NTILES, 256, 0, stream>>>(A, Bm, W1T[0], bs[0][1], W2T[0], bs[0][2], ssrc, nof, x0);
    // block 1 (zeroes x1)
    nodeAB_kernel<128, 128><<<NN / 8, 256, 0, stream>>>(x0, W[1][0], bs[1][0], A, Bm, x1);
    edge_mfma_kernel<128><<<NTILES, 256, 0, stream>>>(A, Bm, W1T[1], bs[1][1], W2T[1], bs[1][2], ssrc, nof, x1);
    // block 2 (zeroes x0)
    nodeAB_kernel<128, 128><<<NN / 8, 256, 0, stream>>>(x1, W[2][0], bs[2][0], A, Bm, x0);
    edge_mfma_kernel<128><<<NTILES, 256, 0, stream>>>(A, Bm, W1T[2], bs[2][1], W2T[2], bs[2][2], ssrc, nof, x0);
    // block 3 (zeroes out) -> d_out
    nodeAB_kernel<128, 16><<<NN / 8, 256, 0, stream>>>(x0, W[3][0], bs[3][0], A, Bm, out);
    edge_mfma_kernel<16><<<NTILES, 256, 0, stream>>>(A, Bm, W1T[3], bs[3][1], W2T[3], bs[3][2], ssrc, nof, out);
}